// Round 7
// baseline (497.410 us; speedup 1.0000x reference)
//
#include <hip/hip_runtime.h>
#include <hip/hip_bf16.h>

// Problem constants (fixed by reference setup_inputs).
#define T_TOTAL 2048
#define BATCH   128
#define NIN     256
#define NOUT    128

// Suffix-scan formulation: delta_w[o,i] = sum_{t,b} in[t,b,i] * rout[t,b,o],
// rout[t] = out[t] + 0.5*rout[t+1]  (reverse scan of the SMALL tensor).
// Block = (batch-pair, T-chunk), 1024 threads = 16 waves = 4 m-tiles x 4 n-groups.
// Lane owns one (b,o) rout chain in registers; its 8 scanned values per chunk
// ARE the MFMA A-fragment (A[m=l31][k=kh*8+j], k = b_pair*8 + t_local).
// B operand = raw binary in-spikes (bf16 = fp32 high half, exact), read as
// strided dwords that hit L2 because a "pump" (volatile contiguous dwordx4
// loads, results discarded) streams each chunk's rows into L2 two chunks
// ahead. HBM sees only contiguous 1-KB bursts. No LDS, no barriers.
#define TC      512                 // timesteps per block
#define NTC     (T_TOTAL / TC)      // 4
#define NBP     (BATCH / 2)         // 64 batch pairs
#define NBLOCKS (NBP * NTC)         // 256
#define WARM    32                  // suffix warm-up steps (0.5^32 ~ 2e-10)
#define CT      8                   // timesteps per k-chunk (K = 16 = 2b x 8t)
#define NCH     (TC / CT)           // 64 chunks per block

#define STRI    (BATCH * NIN)       // 32768 floats per timestep (in)
#define STRO    (BATCH * NOUT)      // 16384 floats per timestep (outs)
#define OUT_ELEMS (NOUT * NIN)      // 32768

typedef __attribute__((ext_vector_type(8)))  __bf16 bf16x8;
typedef __attribute__((ext_vector_type(2)))  __bf16 bf16x2;
typedef __attribute__((ext_vector_type(16))) float  f32x16;
typedef __attribute__((ext_vector_type(4)))  float  f32x4;

// packed f32x2 -> bf16x2 (RTNE) for rout values
static __device__ __forceinline__ unsigned pack_bf16(float a, float b) {
    bf16x2 v = { (__bf16)a, (__bf16)b };
    union { bf16x2 v; unsigned u; } c; c.v = v; return c.u;
}
// binary fp32 pair -> bf16 pair: exact via high-16 extraction (values are 0/1)
static __device__ __forceinline__ unsigned pack_bin(float a, float b) {
    return (__float_as_uint(a) >> 16) | (__float_as_uint(b) & 0xFFFF0000u);
}
static __device__ __forceinline__ bf16x8 frag4(unsigned w0, unsigned w1,
                                               unsigned w2, unsigned w3) {
    union { unsigned u[4]; bf16x8 f; } c;
    c.u[0] = w0; c.u[1] = w1; c.u[2] = w2; c.u[3] = w3; return c.f;
}

__global__ __launch_bounds__(1024, 4)   // 16 waves/CU, VGPR cap 128
void stdp_main(const float* __restrict__ in, const float* __restrict__ outs,
               float* __restrict__ dst, int use_atomic)
{
    const int tid  = threadIdx.x;
    const int lane = tid & 63;
    const int l31  = lane & 31;
    const int kh   = lane >> 5;          // batch-in-pair (MFMA k-half)
    const int wv   = tid >> 6;           // 16 waves
    const int mt   = wv & 3;             // m-tile (o block)
    const int ng   = wv >> 2;            // n-group: n-tiles ng*2, ng*2+1

    const int tc = blockIdx.x & 3;
    const int bp = blockIdx.x >> 2;
    const int b0 = bp * 2;
    const int t_hi = (tc + 1) * TC;      // exclusive top; chunks walk downward

    // lane's rout chain: (b = b0+kh, o = mt*32+l31)
    const size_t ot_ch  = (size_t)(b0 + kh) * NOUT + mt * 32 + l31;
    const size_t in_off = (size_t)(b0 + kh) * NIN;

    // pump: wave wv covers in-row (t=tb+ (wv&7), b = b0+(wv>>3)); waves 8-15
    // additionally pump the outs row (both batches = 1 KB contiguous).
    const int pj = wv & 7, pd = wv >> 3;

    auto pump = [&](int tp) {
        volatile const f32x4* p1 = (volatile const f32x4*)
            &in[(size_t)(tp + pj) * STRI + (size_t)(b0 + pd) * NIN + lane * 4];
        f32x4 x = *p1; (void)x;
        if (pd) {
            volatile const f32x4* p2 = (volatile const f32x4*)
                &outs[(size_t)(tp + pj) * STRO + (size_t)b0 * NOUT + lane * 4];
            f32x4 y = *p2; (void)y;
        }
    };

    float r = 0.f;   // rout state; invariant: entering chunk at t_base, r = rout[t_base+8]

    // ---- suffix warm-up: 32 future timesteps, descending ----
    if (tc < NTC - 1) {
        for (int t = t_hi + WARM - 8; t >= t_hi; t -= 8) {
            float v[8];
#pragma unroll
            for (int u = 0; u < 8; ++u) v[u] = outs[(size_t)(t + u) * STRO + ot_ch];
#pragma unroll
            for (int u = 7; u >= 0; --u) r = v[u] + 0.5f * r;
        }
    }

    f32x16 acc[2];
    acc[0] = (f32x16)(0.f);
    acc[1] = (f32x16)(0.f);

    // pre-pump chunks 0 and 1
    pump(t_hi - CT);
    pump(t_hi - 2 * CT);

    for (int c = 0; c < NCH; ++c) {
        const int tb = t_hi - (c + 1) * CT;

        if (c + 2 < NCH) pump(tb - 2 * CT);   // stream chunk c+2 into L2

        // chain feed (strided 512 B, L2-hit after pump)
        float ov[8];
#pragma unroll
        for (int j = 0; j < 8; ++j) ov[j] = outs[(size_t)(tb + j) * STRO + ot_ch];

        // B operand: raw binary in-spikes for this wave's 2 n-tiles (L2-hit)
        float bv[2][8];
#pragma unroll
        for (int n = 0; n < 2; ++n) {
            const size_t io = in_off + (ng * 2 + n) * 32 + l31;
#pragma unroll
            for (int j = 0; j < 8; ++j) bv[n][j] = in[(size_t)(tb + j) * STRI + io];
        }

        // reverse scan (exact fp32): r = out[t] + 0.5*r, t descending
        float rr[8];
#pragma unroll
        for (int j = 7; j >= 0; --j) { r = ov[j] + 0.5f * r; rr[j] = r; }

        const bf16x8 afrag = frag4(pack_bf16(rr[0], rr[1]), pack_bf16(rr[2], rr[3]),
                                   pack_bf16(rr[4], rr[5]), pack_bf16(rr[6], rr[7]));
#pragma unroll
        for (int n = 0; n < 2; ++n) {
            const bf16x8 bfrag = frag4(pack_bin(bv[n][0], bv[n][1]),
                                       pack_bin(bv[n][2], bv[n][3]),
                                       pack_bin(bv[n][4], bv[n][5]),
                                       pack_bin(bv[n][6], bv[n][7]));
            acc[n] = __builtin_amdgcn_mfma_f32_32x32x16_bf16(afrag, bfrag, acc[n], 0, 0, 0);
        }
    }

    // ---- epilogue: D col = l31 -> i, row = (r&3)+8*(r>>2)+4*kh -> o ----
    if (use_atomic) {
#pragma unroll
        for (int n = 0; n < 2; ++n) {
            const int icol = (ng * 2 + n) * 32 + l31;
#pragma unroll
            for (int q = 0; q < 16; ++q) {
                const int row = (q & 3) + 8 * (q >> 2) + 4 * kh;
                atomicAdd(&dst[(mt * 32 + row) * NIN + icol], acc[n][q]);
            }
        }
    } else {
        float* base = dst + (size_t)blockIdx.x * OUT_ELEMS;
#pragma unroll
        for (int n = 0; n < 2; ++n) {
            const int icol = (ng * 2 + n) * 32 + l31;
#pragma unroll
            for (int q = 0; q < 16; ++q) {
                const int row = (q & 3) + 8 * (q >> 2) + 4 * kh;
                base[(mt * 32 + row) * NIN + icol] = acc[n][q];
            }
        }
    }
}

__global__ void zero_kernel(float* p, int n) {
    int i = blockIdx.x * blockDim.x + threadIdx.x;
    if (i < n) p[i] = 0.f;
}

// Sum the 256 per-block partials.
__global__ __launch_bounds__(256)
void reduce_kernel(const float* __restrict__ ws, float* __restrict__ outp) {
    const int idx = blockIdx.x * 256 + threadIdx.x;
    float s = 0.f;
    for (int k = 0; k < NBLOCKS; k += 16) {
        float v[16];
#pragma unroll
        for (int u = 0; u < 16; ++u) v[u] = ws[(size_t)(k + u) * OUT_ELEMS + idx];
#pragma unroll
        for (int u = 0; u < 16; ++u) s += v[u];
    }
    outp[idx] = s;
}

extern "C" void kernel_launch(void* const* d_in, const int* in_sizes, int n_in,
                              void* d_out, int out_size, void* d_ws, size_t ws_size,
                              hipStream_t stream) {
    const float* in   = (const float*)d_in[0];
    const float* outs = (const float*)d_in[1];
    float* out = (float*)d_out;
    float* ws  = (float*)d_ws;

    if (ws_size >= (size_t)NBLOCKS * OUT_ELEMS * sizeof(float)) {
        // per-block partials (32 MB ws) + reduce
        stdp_main<<<NBLOCKS, 1024, 0, stream>>>(in, outs, ws, 0);
        reduce_kernel<<<OUT_ELEMS / 256, 256, 0, stream>>>(ws, out);
    } else {
        // fallback: fp32 atomics straight into d_out
        zero_kernel<<<(OUT_ELEMS + 255) / 256, 256, 0, stream>>>(out, OUT_ELEMS);
        stdp_main<<<NBLOCKS, 1024, 0, stream>>>(in, outs, out, 1);
    }
}